// Round 12
// baseline (102.280 us; speedup 1.0000x reference)
//
#include <hip/hip_runtime.h>
#include <math.h>

// Problem constants (from reference): B=8, C=512, CI=128, H=W=64
constexpr int Cc  = 512;
constexpr int CIc = 128;
constexpr int Bc  = 8;
constexpr int Nc  = 4096;   // H*W
constexpr int Mc  = 1024;   // (H/2)*(W/2)

typedef __bf16 bf16x8 __attribute__((ext_vector_type(8)));
typedef float  f32x4  __attribute__((ext_vector_type(4)));
typedef float  f32x16 __attribute__((ext_vector_type(16)));

__device__ __forceinline__ unsigned short f2bf(float f) {
  unsigned u = __float_as_uint(f);
  u += 0x7fffu + ((u >> 16) & 1u);
  return (unsigned short)(u >> 16);
}
__device__ __forceinline__ float bf2f(unsigned short h) {
  return __uint_as_float((unsigned)h << 16);
}
__device__ __forceinline__ unsigned pack2bf(float lo, float hi) {
  return (unsigned)f2bf(lo) | ((unsigned)f2bf(hi) << 16);
}

// async global->LDS DMA, 16B per lane; LDS dest = wave-uniform base + lane*16
__device__ __forceinline__ void gload16(const void* g, void* lds) {
  __builtin_amdgcn_global_load_lds(
      (const __attribute__((address_space(1))) unsigned int*)g,
      (__attribute__((address_space(3))) unsigned int*)lds, 16, 0, 0);
}

// ---------------------------------------------------------------------------
// Kernel 0: weight/bias prep. wcat [384][512] bf16 (rows: 0-127 theta,
// 128-255 phi, 256-383 g), wwb [512][128] bf16, bcat [384] f32.
// ---------------------------------------------------------------------------
__global__ __launch_bounds__(256) void k_prep(
    const float* __restrict__ gw, const float* __restrict__ pw,
    const float* __restrict__ tw, const float* __restrict__ Ww,
    const float* __restrict__ gb, const float* __restrict__ pb,
    const float* __restrict__ tb,
    unsigned short* __restrict__ wcat, unsigned short* __restrict__ wwb,
    float* __restrict__ bcat) {
  int i = blockIdx.x * 256 + threadIdx.x;
  if (i < 49152) {                 // wcat: 384 rows x 128 float4
    int c = i >> 7, q = i & 127;
    const float* src = (c < 128) ? tw + (size_t)c * 512
                     : (c < 256) ? pw + (size_t)(c - 128) * 512
                                 : gw + (size_t)(c - 256) * 512;
    float4 v = *(const float4*)(src + q * 4);
    ushort4 o;
    o.x = f2bf(v.x); o.y = f2bf(v.y); o.z = f2bf(v.z); o.w = f2bf(v.w);
    *(ushort4*)(wcat + (size_t)c * 512 + q * 4) = o;
  } else if (i < 65536) {          // wwb: 512 rows x 32 float4
    int i2 = i - 49152;
    int c = i2 >> 5, q = i2 & 31;
    float4 v = *(const float4*)(Ww + (size_t)c * 128 + q * 4);
    ushort4 o;
    o.x = f2bf(v.x); o.y = f2bf(v.y); o.z = f2bf(v.z); o.w = f2bf(v.w);
    *(ushort4*)(wwb + (size_t)c * 128 + q * 4) = o;
  } else if (i < 65920) {
    int j = i - 65536;
    bcat[j] = (j < 128) ? tb[j] : (j < 256) ? pb[j - 128] : gb[j - 256];
  }
}

// ---------------------------------------------------------------------------
// Kernel 1: all three projections as one MFMA GEMM + FUSED 2x2 maxpool.
// THIS ROUND: 32x32x16 MFMA. 8 waves = 4 row-groups x 2 col-groups; each
// wave computes 32 n-rows x 192 c_out, so each W B-fragment read feeds 2x
// the FLOPs: block W LDS traffic halves (384->192 KB/chunk). Staging is
// the proven R6 2-buffer vmcnt(0) pattern. x loads go straight to regs.
// 32x32 D-layout (verified): col=lane&31, row=(reg&3)+8*(reg>>2)+4*(lane>>5).
// ---------------------------------------------------------------------------
__global__ __launch_bounds__(512) void k_conv_all(
    const float* __restrict__ x, const unsigned short* __restrict__ wcat,
    const float* __restrict__ bcat,
    unsigned short* __restrict__ theta_t, unsigned short* __restrict__ phi_t,
    unsigned short* __restrict__ gbuf) {
  __shared__ __align__(16) char smem[98304];   // W dbuf [2][49152]; epilogue alias
  const int b = blockIdx.y, h2 = blockIdx.x, n0 = h2 * 128;
  const int t = threadIdx.x;
  const int w = t >> 6, l = t & 63;
  const int rg = w >> 1, cg = w & 1;          // row-group (0..3), col-group (0..1)
  const int l32 = l & 31, lh = l >> 5;        // lane index within 32, lane half

  // W staging (unchanged layout): tile [384 c][64 k] bf16, swizzled 128B rows,
  // linear LDS dest + pre-swizzled source.
  const char* wsrc = (const char*)wcat;   // row stride 1024 B
  int woff[6];
#pragma unroll
  for (int i = 0; i < 6; ++i) {
    int r = (w * 6 + i) * 8 + (l >> 3);
    woff[i] = r * 1024 + (((l & 7) * 16) ^ ((r & 7) << 4));
  }

  // x base for this lane's A-row: n = n0 + rg*32 + l32
  const float* xb = x + (size_t)b * Cc * Nc + n0 + rg * 32 + l32;

  // A-frag k coverage per 32x32x16 step: lane holds k = 8*lh + j (j=0..7)
  float xraw[32];
#define LOADX(k0_)                                                          \
  {                                                                         \
    _Pragma("unroll")                                                       \
    for (int f = 0; f < 4; ++f)                                             \
      _Pragma("unroll")                                                     \
      for (int j = 0; j < 8; ++j)                                           \
        xraw[f * 8 + j] = xb[(size_t)((k0_) + f * 16 + 8 * lh + j) * Nc];   \
  }
#define STAGEW(buf_, k0_)                                                   \
  {                                                                         \
    char* dst_ = smem + (buf_) * 49152;                                     \
    _Pragma("unroll")                                                       \
    for (int i = 0; i < 6; ++i)                                             \
      gload16(wsrc + (size_t)(k0_) * 2 + woff[i], dst_ + (w * 6 + i) * 1024); \
  }

  f32x16 acc[6];
#pragma unroll
  for (int tt = 0; tt < 6; ++tt)
#pragma unroll
    for (int r = 0; r < 16; ++r) acc[tt][r] = 0.f;

  // prologue
  LOADX(0);
  STAGEW(0, 0);
  asm volatile("s_waitcnt vmcnt(0)" ::: "memory");
  __builtin_amdgcn_s_barrier();

#pragma unroll
  for (int c = 0; c < 8; ++c) {
    // convert current chunk's x to 4 A-frags (frees xraw for next prefetch)
    bf16x8 af[4];
#pragma unroll
    for (int f = 0; f < 4; ++f) {
      union { unsigned u[4]; bf16x8 v; } ab;
#pragma unroll
      for (int q = 0; q < 4; ++q)
        ab.u[q] = pack2bf(xraw[f * 8 + 2 * q], xraw[f * 8 + 2 * q + 1]);
      af[f] = ab.v;
    }
    if (c < 7) {
      LOADX((c + 1) * 64);
      STAGEW((c + 1) & 1, (c + 1) * 64);
    }
    const char* Wb = smem + (c & 1) * 49152;
    __builtin_amdgcn_s_setprio(1);
#pragma unroll
    for (int ks = 0; ks < 4; ++ks)
#pragma unroll
      for (int tt = 0; tt < 6; ++tt) {
        int r = cg * 192 + tt * 32 + l32;
        bf16x8 bfr = *(const bf16x8*)(
            Wb + r * 128 + ((ks * 32 + 16 * lh) ^ ((r & 7) << 4)));
        acc[tt] =
            __builtin_amdgcn_mfma_f32_32x32x16_bf16(af[ks], bfr, acc[tt], 0, 0, 0);
      }
    __builtin_amdgcn_s_setprio(0);
    if (c < 7) {
      asm volatile("s_waitcnt vmcnt(0)" ::: "memory");
      __builtin_amdgcn_s_barrier();
    }
  }
#undef LOADX
#undef STAGEW

  __syncthreads();   // all MFMA LDS reads done before aliasing smem
  unsigned short* PG = (unsigned short*)smem;            // [128][264]
  unsigned short* Yt = (unsigned short*)(smem + 67584);  // [64][136]

  // D mapping: c = cg*192 + tt*32 + l32; n_local = rg*32 + (reg&3)+8*(reg>>2)+4*lh
  // phase 1: phi/g (c in [128,384)) -> PG by all waves;
  //          theta (c in [0,128)) half-0 (rows 0..63 = rg 0,1) -> Yt by cg==0.
#pragma unroll
  for (int tt = 0; tt < 6; ++tt) {
    if (cg == 1 || tt >= 4) {
      int c = cg * 192 + tt * 32 + l32;
      float bv = bcat[c];
#pragma unroll
      for (int reg = 0; reg < 16; ++reg) {
        int nl = rg * 32 + (reg & 3) + 8 * (reg >> 2) + 4 * lh;
        PG[nl * 264 + c - 128] = f2bf(acc[tt][reg] + bv);
      }
    }
  }
  if (cg == 0 && rg < 2) {
#pragma unroll
    for (int tt = 0; tt < 4; ++tt) {
      int c = tt * 32 + l32;
      float bv = bcat[c];
#pragma unroll
      for (int reg = 0; reg < 16; ++reg) {
        int nl = rg * 32 + (reg & 3) + 8 * (reg >> 2) + 4 * lh;   // 0..63
        Yt[nl * 136 + c] = f2bf(acc[tt][reg] + bv);
      }
    }
  }
  __syncthreads();
  // theta half-0 global write
#pragma unroll
  for (int it = 0; it < 2; ++it) {
    int idx = it * 512 + t, n = idx >> 4, j = idx & 15;
    *(bf16x8*)(theta_t + (((size_t)(b * Nc + n0 + n)) << 7) + j * 8) =
        *(const bf16x8*)(Yt + n * 136 + j * 8);
  }
  // pooled phi: [32 m][128 ci]
  {
    int mloc = t >> 4, j = t & 15;
    const unsigned short* r0 = &PG[(2 * mloc) * 264 + j * 8];
    const unsigned short* r1 = &PG[(2 * mloc + 1) * 264 + j * 8];
    const unsigned short* r2 = &PG[(64 + 2 * mloc) * 264 + j * 8];
    const unsigned short* r3 = &PG[(65 + 2 * mloc) * 264 + j * 8];
    unsigned short o[8];
#pragma unroll
    for (int q = 0; q < 8; ++q)
      o[q] = f2bf(fmaxf(fmaxf(bf2f(r0[q]), bf2f(r1[q])),
                        fmaxf(bf2f(r2[q]), bf2f(r3[q]))));
    unsigned short* dp = phi_t + (((size_t)(b * Mc + h2 * 32 + mloc)) << 7) + j * 8;
    *(ushort4*)dp = *(ushort4*)o;
    *(ushort4*)(dp + 4) = *(ushort4*)(o + 4);
  }
  // pooled g (transposed)
  {
    int ci = t >> 2, mq = t & 3;
    unsigned short tmp[8];
#pragma unroll
    for (int q = 0; q < 8; ++q) {
      int w2 = mq * 8 + q;
      float m0 = fmaxf(
          fmaxf(bf2f(PG[(2 * w2) * 264 + 128 + ci]),
                bf2f(PG[(2 * w2 + 1) * 264 + 128 + ci])),
          fmaxf(bf2f(PG[(64 + 2 * w2) * 264 + 128 + ci]),
                bf2f(PG[(65 + 2 * w2) * 264 + 128 + ci])));
      tmp[q] = f2bf(m0);
    }
    unsigned short* dst = gbuf + ((size_t)(b * CIc + ci)) * Mc + h2 * 32 + mq * 8;
    *(ushort4*)(dst) = *(ushort4*)(tmp);
    *(ushort4*)(dst + 4) = *(ushort4*)(tmp + 4);
  }
  __syncthreads();
  // theta half-1 (rows 64..127 = rg 2,3) -> Yt
  if (cg == 0 && rg >= 2) {
#pragma unroll
    for (int tt = 0; tt < 4; ++tt) {
      int c = tt * 32 + l32;
      float bv = bcat[c];
#pragma unroll
      for (int reg = 0; reg < 16; ++reg) {
        int nl = rg * 32 + (reg & 3) + 8 * (reg >> 2) + 4 * lh - 64;  // 0..63
        Yt[nl * 136 + c] = f2bf(acc[tt][reg] + bv);
      }
    }
  }
  __syncthreads();
#pragma unroll
  for (int it = 0; it < 2; ++it) {
    int idx = it * 512 + t, n = idx >> 4, j = idx & 15;
    *(bf16x8*)(theta_t + (((size_t)(b * Nc + n0 + 64 + n)) << 7) + j * 8) =
        *(const bf16x8*)(Yt + n * 136 + j * 8);
  }
}

// ---------------------------------------------------------------------------
// Kernel 3: MFMA flash attention (unchanged from passing rounds 10/11:
// swapped QK^T + in-lane softmax, dbuf async staging).
// ---------------------------------------------------------------------------
__global__ __launch_bounds__(256) void k_attn_mfma(
    const unsigned short* __restrict__ theta_t,
    const unsigned short* __restrict__ phi_t,
    const unsigned short* __restrict__ gv,
    unsigned short* __restrict__ y_t) {
  __shared__ __align__(16) char Kb[2][16384];   // [64 m][256B] swizzled
  __shared__ __align__(16) char Vb[2][16384];   // [128 ci][128B] swizzled
  __shared__ __align__(16) unsigned Psd[4][16][36];  // P dwords, 144B rows
  const int b = blockIdx.y, n0 = blockIdx.x * 64;
  const int tid = threadIdx.x;
  const int w = tid >> 6, l = tid & 63;
  const int lr = l & 15, lg = l >> 4;

  const int krow_l = l >> 4, kchunk = (l & 15) * 16;
  const int vrow_l = l >> 3, vchunk = (l & 7) * 16;
  int koff[4], voff[4];
#pragma unroll
  for (int i = 0; i < 4; ++i) {
    int kr = w * 16 + i * 4 + krow_l;
    koff[i] = kr * 256 + (kchunk ^ ((kr & 7) << 4));
    int vr = w * 32 + i * 8 + vrow_l;
    voff[i] = vr * 2048 + (vchunk ^ ((vr & 7) << 4));
  }
  const char* kbase = (const char*)(phi_t + (((size_t)(b * Mc)) << 7));
  const char* vbase = (const char*)(gv + (((size_t)b) << 17));

  auto stage = [&](int buf, int t) {
#pragma unroll
    for (int i = 0; i < 4; ++i)
      gload16(kbase + t * 16384 + koff[i], &Kb[buf][(w * 4 + i) * 1024]);
#pragma unroll
    for (int i = 0; i < 4; ++i)
      gload16(vbase + t * 128 + voff[i], &Vb[buf][(w * 4 + i) * 1024]);
  };

  bf16x8 qf[4];
  {
    const unsigned short* qp =
        theta_t + (((size_t)(b * Nc + n0 + w * 16 + lr)) << 7);
#pragma unroll
    for (int kk = 0; kk < 4; ++kk)
      qf[kk] = *(const bf16x8*)(qp + kk * 32 + lg * 8);
  }
  f32x4 of[8];
#pragma unroll
  for (int ct = 0; ct < 8; ++ct) of[ct] = (f32x4){0.f, 0.f, 0.f, 0.f};
  float run_m = -1e30f, run_l = 0.f;

  stage(0, 0);
  asm volatile("s_waitcnt vmcnt(0)" ::: "memory");
  __builtin_amdgcn_s_barrier();

  for (int t = 0; t < Mc / 64; ++t) {
    const int cur = t & 1;
    if (t + 1 < Mc / 64) stage(cur ^ 1, t + 1);
    const char* Ks = Kb[cur];
    const char* Vs = Vb[cur];
    f32x4 sm[4];
    __builtin_amdgcn_s_setprio(1);
#pragma unroll
    for (int mt = 0; mt < 4; ++mt) {
      f32x4 s = (f32x4){0.f, 0.f, 0.f, 0.f};
#pragma unroll
      for (int kk = 0; kk < 4; ++kk) {
        bf16x8 kf = *(const bf16x8*)(
            Ks + (mt * 16 + lr) * 256 + ((kk * 64 + lg * 16) ^ ((lr & 7) << 4)));
        s = __builtin_amdgcn_mfma_f32_16x16x32_bf16(kf, qf[kk], s, 0, 0, 0);
      }
      sm[mt] = s;
    }
    __builtin_amdgcn_s_setprio(0);
    float mx;
    {
      float m0 = fmaxf(fmaxf(sm[0][0], sm[0][1]), fmaxf(sm[0][2], sm[0][3]));
      float m1 = fmaxf(fmaxf(sm[1][0], sm[1][1]), fmaxf(sm[1][2], sm[1][3]));
      float m2 = fmaxf(fmaxf(sm[2][0], sm[2][1]), fmaxf(sm[2][2], sm[2][3]));
      float m3 = fmaxf(fmaxf(sm[3][0], sm[3][1]), fmaxf(sm[3][2], sm[3][3]));
      mx = fmaxf(fmaxf(m0, m1), fmaxf(m2, m3));
      mx = fmaxf(mx, __shfl_xor(mx, 16));
      mx = fmaxf(mx, __shfl_xor(mx, 32));
    }
    if (__any(mx > run_m + 8.f)) {
      float nm = fmaxf(run_m, mx);
      float sc = __expf(run_m - nm);
      run_m = nm;
      run_l *= sc;
#pragma unroll
      for (int reg = 0; reg < 4; ++reg) {
        float scr = __shfl(sc, lg * 20 + reg);
#pragma unroll
        for (int ct = 0; ct < 8; ++ct) of[ct][reg] *= scr;
      }
    }
    unsigned pk[4][2];
    float rowsum = 0.f;
#pragma unroll
    for (int mt = 0; mt < 4; ++mt) {
      float p0 = __expf(sm[mt][0] - run_m);
      float p1 = __expf(sm[mt][1] - run_m);
      float p2 = __expf(sm[mt][2] - run_m);
      float p3 = __expf(sm[mt][3] - run_m);
      rowsum += (p0 + p1) + (p2 + p3);
      asm("v_cvt_pk_bf16_f32 %0, %1, %2" : "=v"(pk[mt][0]) : "v"(p0), "v"(p1));
      asm("v_cvt_pk_bf16_f32 %0, %1, %2" : "=v"(pk[mt][1]) : "v"(p2), "v"(p3));
    }
    rowsum += __shfl_xor(rowsum, 16);
    rowsum += __shfl_xor(rowsum, 32);
    run_l += rowsum;
#pragma unroll
    for (int mt = 0; mt < 4; ++mt) {
      Psd[w][lr][8 * mt + 2 * lg + 0] = pk[mt][0];
      Psd[w][lr][8 * mt + 2 * lg + 1] = pk[mt][1];
    }
    bf16x8 pa0 = *(const bf16x8*)&Psd[w][lr][lg * 4];
    bf16x8 pa1 = *(const bf16x8*)&Psd[w][lr][16 + lg * 4];
    __builtin_amdgcn_s_setprio(1);
#pragma unroll
    for (int ct = 0; ct < 8; ++ct) {
      bf16x8 vf0 = *(const bf16x8*)(
          Vs + (ct * 16 + lr) * 128 + ((lg * 16) ^ ((lr & 7) << 4)));
      of[ct] = __builtin_amdgcn_mfma_f32_16x16x32_bf16(pa0, vf0, of[ct], 0, 0, 0);
      bf16x8 vf1 = *(const bf16x8*)(
          Vs + (ct * 16 + lr) * 128 + ((64 + lg * 16) ^ ((lr & 7) << 4)));
      of[ct] = __builtin_amdgcn_mfma_f32_16x16x32_bf16(pa1, vf1, of[ct], 0, 0, 0);
    }
    __builtin_amdgcn_s_setprio(0);
    asm volatile("s_waitcnt vmcnt(0)" ::: "memory");
    __builtin_amdgcn_s_barrier();
  }
  float invl = 1.f / run_l;
  float invr[4];
#pragma unroll
  for (int reg = 0; reg < 4; ++reg) invr[reg] = __shfl(invl, lg * 20 + reg);
  unsigned short* Ys = (unsigned short*)Kb;
#pragma unroll
  for (int ct = 0; ct < 8; ++ct)
#pragma unroll
    for (int reg = 0; reg < 4; ++reg)
      Ys[(w * 16 + lg * 4 + reg) * 128 + ct * 16 + lr] =
          f2bf(of[ct][reg] * invr[reg]);
  __syncthreads();
#pragma unroll
  for (int it = 0; it < 4; ++it) {
    int i = it * 256 + tid;
    int r = i >> 4, cl = i & 15;
    *(bf16x8*)(y_t + (((size_t)(b * Nc + n0 + r)) << 7) + cl * 8) =
        *(const bf16x8*)(Ys + r * 128 + cl * 8);
  }
}

// ---------------------------------------------------------------------------
// Kernel 4: MFMA W-conv + channels-first LayerNorm + residual.
// (unchanged from passing rounds 9-11: dbuf async W staging)
// ---------------------------------------------------------------------------
__global__ __launch_bounds__(256) void k_wconv_mfma(
    const unsigned short* __restrict__ y_t, const unsigned short* __restrict__ wwb,
    const float* __restrict__ wbias, const float* __restrict__ gamma,
    const float* __restrict__ beta, const float* __restrict__ x,
    float* __restrict__ out) {
  __shared__ __align__(16) char smem[65536];    // W dbuf [2][32768]; epilogue alias
  float* Ys = (float*)smem;                     // epilogue alias [128 c][72 n]
  const int b = blockIdx.y, n0 = blockIdx.x * 64;
  const int t = threadIdx.x;
  const int w = t >> 6, l = t & 63, lr = l & 15, lg = l >> 4;

  int woff[8];
#pragma unroll
  for (int i = 0; i < 8; ++i) {
    int r = (w * 8 + i) * 4 + (l >> 4);
    woff[i] = r * 256 + ((((l & 15) * 16)) ^ ((r & 7) << 4));
  }
  const char* wbase = (const char*)wwb;   // chunk cc at wbase + cc*32768

  auto stageW = [&](int buf, int cc) {
#pragma unroll
    for (int i = 0; i < 8; ++i)
      gload16(wbase + cc * 32768 + woff[i],
              smem + buf * 32768 + (w * 8 + i) * 1024);
  };

  bf16x8 qf[4];
  {
    const unsigned short* qp = y_t + (((size_t)(b * Nc + n0 + w * 16 + lr)) << 7);
#pragma unroll
    for (int kk = 0; kk < 4; ++kk)
      qf[kk] = *(const bf16x8*)(qp + kk * 32 + lg * 8);
  }
  f32x4 acc[32];
#pragma unroll
  for (int i = 0; i < 32; ++i) acc[i] = (f32x4){0.f, 0.f, 0.f, 0.f};

  stageW(0, 0);
  asm volatile("s_waitcnt vmcnt(0)" ::: "memory");
  __builtin_amdgcn_s_barrier();

#pragma unroll
  for (int cc = 0; cc < 4; ++cc) {
    const int cur = cc & 1;
    if (cc < 3) stageW(cur ^ 1, cc + 1);
    const char* WTs = smem + cur * 32768;
    __builtin_amdgcn_s_setprio(1);
#pragma unroll
    for (int tc = 0; tc < 8; ++tc) {
      f32x4 a = acc[cc * 8 + tc];
      int r = tc * 16 + lr;
#pragma unroll
      for (int kk = 0; kk < 4; ++kk) {
        bf16x8 kf = *(const bf16x8*)(
            WTs + r * 256 + ((kk * 64 + lg * 16) ^ ((lr & 7) << 4)));
        a = __builtin_amdgcn_mfma_f32_16x16x32_bf16(qf[kk], kf, a, 0, 0, 0);
      }
      acc[cc * 8 + tc] = a;
    }
    __builtin_amdgcn_s_setprio(0);
    asm volatile("s_waitcnt vmcnt(0)" ::: "memory");
    __builtin_amdgcn_s_barrier();
  }

  float s[4] = {0.f, 0.f, 0.f, 0.f}, q[4] = {0.f, 0.f, 0.f, 0.f};
#pragma unroll
  for (int cc = 0; cc < 4; ++cc)
#pragma unroll
    for (int tc = 0; tc < 8; ++tc) {
      float wb = wbias[cc * 128 + tc * 16 + lr];
      f32x4 a = acc[cc * 8 + tc];
#pragma unroll
      for (int reg = 0; reg < 4; ++reg) {
        a[reg] += wb;
        s[reg] += a[reg];
        q[reg] += a[reg] * a[reg];
      }
      acc[cc * 8 + tc] = a;
    }
  float mu[4], rs[4];
#pragma unroll
  for (int reg = 0; reg < 4; ++reg) {
    float sv = s[reg], qv = q[reg];
    sv += __shfl_xor(sv, 1); qv += __shfl_xor(qv, 1);
    sv += __shfl_xor(sv, 2); qv += __shfl_xor(qv, 2);
    sv += __shfl_xor(sv, 4); qv += __shfl_xor(qv, 4);
    sv += __shfl_xor(sv, 8); qv += __shfl_xor(qv, 8);
    mu[reg] = sv * (1.f / 512.f);
    float var = qv * (1.f / 512.f) - mu[reg] * mu[reg];
    rs[reg] = rsqrtf(var + 1e-5f);
  }
#pragma unroll
  for (int cc = 0; cc < 4; ++cc) {
    __syncthreads();
#pragma unroll
    for (int tc = 0; tc < 8; ++tc) {
      int c = cc * 128 + tc * 16 + lr;
      float ga = gamma[c], be = beta[c];
#pragma unroll
      for (int reg = 0; reg < 4; ++reg)
        Ys[(tc * 16 + lr) * 72 + w * 16 + lg * 4 + reg] =
            (acc[cc * 8 + tc][reg] - mu[reg]) * rs[reg] * ga + be;
    }
    __syncthreads();
#pragma unroll
    for (int it = 0; it < 8; ++it) {
      int idx = it * 256 + t;
      int r = idx >> 4, j = idx & 15;
      float4 v = *(const float4*)&Ys[r * 72 + j * 4];
      size_t gaddr = ((size_t)b * Cc + cc * 128 + r) * Nc + n0 + j * 4;
      float4 xv = *(const float4*)&x[gaddr];
      float4 o;
      o.x = v.x + xv.x; o.y = v.y + xv.y; o.z = v.z + xv.z; o.w = v.w + xv.w;
      *(float4*)&out[gaddr] = o;
    }
  }
}

// ---------------------------------------------------------------------------
extern "C" void kernel_launch(void* const* d_in, const int* in_sizes, int n_in,
                              void* d_out, int out_size, void* d_ws, size_t ws_size,
                              hipStream_t stream) {
  const float* x       = (const float*)d_in[0];
  const float* g_w     = (const float*)d_in[1];
  const float* g_b     = (const float*)d_in[2];
  const float* phi_w   = (const float*)d_in[3];
  const float* phi_b   = (const float*)d_in[4];
  const float* theta_w = (const float*)d_in[5];
  const float* theta_b = (const float*)d_in[6];
  const float* W_w     = (const float*)d_in[7];
  const float* W_b     = (const float*)d_in[8];
  const float* ln_g    = (const float*)d_in[9];
  const float* ln_b    = (const float*)d_in[10];
  float* out = (float*)d_out;

  unsigned short* theta_t = (unsigned short*)d_ws;
  unsigned short* y_t     = theta_t + (size_t)Bc * Nc * CIc;
  unsigned short* phi_t   = y_t + (size_t)Bc * Nc * CIc;
  unsigned short* gbuf    = phi_t + (size_t)Bc * Mc * CIc;
  unsigned short* wcat    = gbuf + (size_t)Bc * Mc * CIc;
  unsigned short* wwb     = wcat + (size_t)384 * 512;
  float*          bcat    = (float*)(wwb + (size_t)512 * 128);

  k_prep<<<dim3(258), dim3(256), 0, stream>>>(
      g_w, phi_w, theta_w, W_w, g_b, phi_b, theta_b, wcat, wwb, bcat);
  k_conv_all<<<dim3(Nc / 128, Bc), dim3(512), 0, stream>>>(
      x, wcat, bcat, theta_t, phi_t, gbuf);
  k_attn_mfma<<<dim3(Nc / 64, Bc), dim3(256), 0, stream>>>(
      theta_t, phi_t, gbuf, y_t);
  k_wconv_mfma<<<dim3(Nc / 64, Bc), dim3(256), 0, stream>>>(
      y_t, wwb, W_b, ln_g, ln_b, x, out);
}

// Round 13
// 100.051 us; speedup vs baseline: 1.0223x; 1.0223x over previous
//
#include <hip/hip_runtime.h>
#include <math.h>

// Problem constants (from reference): B=8, C=512, CI=128, H=W=64
constexpr int Cc  = 512;
constexpr int CIc = 128;
constexpr int Bc  = 8;
constexpr int Nc  = 4096;   // H*W
constexpr int Mc  = 1024;   // (H/2)*(W/2)

typedef __bf16 bf16x8 __attribute__((ext_vector_type(8)));
typedef float  f32x4  __attribute__((ext_vector_type(4)));

__device__ __forceinline__ unsigned short f2bf(float f) {
  unsigned u = __float_as_uint(f);
  u += 0x7fffu + ((u >> 16) & 1u);
  return (unsigned short)(u >> 16);
}
__device__ __forceinline__ float bf2f(unsigned short h) {
  return __uint_as_float((unsigned)h << 16);
}
__device__ __forceinline__ unsigned pack2bf(float lo, float hi) {
  return (unsigned)f2bf(lo) | ((unsigned)f2bf(hi) << 16);
}

// async global->LDS DMA, 16B per lane; LDS dest = wave-uniform base + lane*16
__device__ __forceinline__ void gload16(const void* g, void* lds) {
  __builtin_amdgcn_global_load_lds(
      (const __attribute__((address_space(1))) unsigned int*)g,
      (__attribute__((address_space(3))) unsigned int*)lds, 16, 0, 0);
}

// ---------------------------------------------------------------------------
// Kernel 0: weight/bias prep. wcat [384][512] bf16 (rows: 0-127 theta,
// 128-255 phi, 256-383 g), wwb [512][128] bf16, bcat [384] f32.
// THIS ROUND: theta rows/bias pre-scaled by log2(e) so attention scores are
// produced in the log2 domain -> attn uses raw v_exp_f32 (exp2) with no mul.
// ---------------------------------------------------------------------------
__global__ __launch_bounds__(256) void k_prep(
    const float* __restrict__ gw, const float* __restrict__ pw,
    const float* __restrict__ tw, const float* __restrict__ Ww,
    const float* __restrict__ gb, const float* __restrict__ pb,
    const float* __restrict__ tb,
    unsigned short* __restrict__ wcat, unsigned short* __restrict__ wwb,
    float* __restrict__ bcat) {
  constexpr float L2E = 1.4426950408889634f;
  int i = blockIdx.x * 256 + threadIdx.x;
  if (i < 49152) {                 // wcat: 384 rows x 128 float4
    int c = i >> 7, q = i & 127;
    const float* src = (c < 128) ? tw + (size_t)c * 512
                     : (c < 256) ? pw + (size_t)(c - 128) * 512
                                 : gw + (size_t)(c - 256) * 512;
    float sc = (c < 128) ? L2E : 1.f;
    float4 v = *(const float4*)(src + q * 4);
    ushort4 o;
    o.x = f2bf(v.x * sc); o.y = f2bf(v.y * sc);
    o.z = f2bf(v.z * sc); o.w = f2bf(v.w * sc);
    *(ushort4*)(wcat + (size_t)c * 512 + q * 4) = o;
  } else if (i < 65536) {          // wwb: 512 rows x 32 float4
    int i2 = i - 49152;
    int c = i2 >> 5, q = i2 & 31;
    float4 v = *(const float4*)(Ww + (size_t)c * 128 + q * 4);
    ushort4 o;
    o.x = f2bf(v.x); o.y = f2bf(v.y); o.z = f2bf(v.z); o.w = f2bf(v.w);
    *(ushort4*)(wwb + (size_t)c * 128 + q * 4) = o;
  } else if (i < 65920) {
    int j = i - 65536;
    bcat[j] = (j < 128) ? tb[j] * L2E : (j < 256) ? pb[j - 128] : gb[j - 256];
  }
}

// ---------------------------------------------------------------------------
// Kernel 1: all three projections as one MFMA GEMM + FUSED 2x2 maxpool.
// (REVERTED to round-11 version: 16x16 MFMA, W triple-buffered, 2-deep
// pipeline with counted vmcnt — best measured configuration.)
// ---------------------------------------------------------------------------
__global__ __launch_bounds__(512) void k_conv_all(
    const float* __restrict__ x, const unsigned short* __restrict__ wcat,
    const float* __restrict__ bcat,
    unsigned short* __restrict__ theta_t, unsigned short* __restrict__ phi_t,
    unsigned short* __restrict__ gbuf) {
  __shared__ __align__(16) char smem[147456];  // W 3-buf [3][49152]; epilogue alias
  const int b = blockIdx.y, h2 = blockIdx.x, n0 = h2 * 128;
  const int t = threadIdx.x;
  const int w = t >> 6, l = t & 63, lr = l & 15, lg = l >> 4;

  const char* wsrc = (const char*)wcat;   // row stride 1024 B
  int woff[6];
#pragma unroll
  for (int i = 0; i < 6; ++i) {
    int r = (w * 6 + i) * 8 + (l >> 3);
    woff[i] = r * 1024 + (((l & 7) * 16) ^ ((r & 7) << 4));
  }

  const float* xb = x + (size_t)b * Cc * Nc + n0 + w * 16 + lr;

  float xraw0[16], xraw1[16];
#define LOADX(dst_, k0_)                                                  \
  {                                                                       \
    _Pragma("unroll")                                                     \
    for (int ks = 0; ks < 2; ++ks)                                        \
      _Pragma("unroll")                                                   \
      for (int j = 0; j < 8; ++j)                                         \
        dst_[ks * 8 + j] = xb[(size_t)((k0_) + ks * 32 + lg * 8 + j) * Nc]; \
  }
#define STAGEW(buf_, k0_)                                                 \
  {                                                                       \
    char* dst_ = smem + (buf_) * 49152;                                   \
    _Pragma("unroll")                                                     \
    for (int i = 0; i < 6; ++i)                                           \
      gload16(wsrc + (size_t)(k0_) * 2 + woff[i], dst_ + (w * 6 + i) * 1024); \
  }
#define CONVERT(src_)                                                     \
  {                                                                       \
    _Pragma("unroll")                                                     \
    for (int ks = 0; ks < 2; ++ks) {                                      \
      union { unsigned u[4]; bf16x8 v; } ab;                              \
      _Pragma("unroll")                                                   \
      for (int q = 0; q < 4; ++q)                                         \
        ab.u[q] = pack2bf(src_[ks * 8 + 2 * q], src_[ks * 8 + 2 * q + 1]); \
      af[ks] = ab.v;                                                      \
    }                                                                     \
  }

  f32x4 acc[24];
#pragma unroll
  for (int tc = 0; tc < 24; ++tc) acc[tc] = (f32x4){0.f, 0.f, 0.f, 0.f};

  // prologue: chunks 0 and 1 in flight
  STAGEW(0, 0);
  LOADX(xraw0, 0);
  STAGEW(1, 64);
  LOADX(xraw1, 64);
  asm volatile("s_waitcnt vmcnt(22)" ::: "memory");  // chunk-0 W + x landed
  __builtin_amdgcn_s_barrier();

#pragma unroll
  for (int c = 0; c < 8; ++c) {
    bf16x8 af[2];
    if ((c & 1) == 0) {
      CONVERT(xraw0);
      if (c < 6) { STAGEW((c + 2) % 3, (c + 2) * 64); LOADX(xraw0, (c + 2) * 64); }
    } else {
      CONVERT(xraw1);
      if (c < 6) { STAGEW((c + 2) % 3, (c + 2) * 64); LOADX(xraw1, (c + 2) * 64); }
    }
    const char* Wb = smem + (c % 3) * 49152;
    __builtin_amdgcn_s_setprio(1);
#pragma unroll
    for (int ks = 0; ks < 2; ++ks)
#pragma unroll
      for (int tc = 0; tc < 24; ++tc) {
        int r = tc * 16 + lr;
        bf16x8 bfr = *(const bf16x8*)(
            Wb + r * 128 + ((lg * 16 + ks * 64) ^ ((lr & 7) << 4)));
        acc[tc] = __builtin_amdgcn_mfma_f32_16x16x32_bf16(af[ks], bfr, acc[tc], 0, 0, 0);
      }
    __builtin_amdgcn_s_setprio(0);
    if (c < 6) {
      asm volatile("s_waitcnt vmcnt(22)" ::: "memory");
      __builtin_amdgcn_s_barrier();
    } else if (c == 6) {
      asm volatile("s_waitcnt vmcnt(16)" ::: "memory");
      __builtin_amdgcn_s_barrier();
    }
  }
#undef LOADX
#undef STAGEW
#undef CONVERT

  __syncthreads();   // all MFMA LDS reads done before aliasing smem
  unsigned short* PG = (unsigned short*)smem;            // [128][264]
  unsigned short* Yt = (unsigned short*)(smem + 67584);  // [64][136]
  const int rbase = w * 16 + lg * 4;

#pragma unroll
  for (int tc = 8; tc < 24; ++tc) {
    float bv = bcat[tc * 16 + lr];
#pragma unroll
    for (int reg = 0; reg < 4; ++reg)
      PG[(rbase + reg) * 264 + tc * 16 + lr - 128] = f2bf(acc[tc][reg] + bv);
  }
  if (w < 4) {
#pragma unroll
    for (int tc = 0; tc < 8; ++tc) {
      float bv = bcat[tc * 16 + lr];
#pragma unroll
      for (int reg = 0; reg < 4; ++reg)
        Yt[(rbase + reg) * 136 + tc * 16 + lr] = f2bf(acc[tc][reg] + bv);
    }
  }
  __syncthreads();
#pragma unroll
  for (int it = 0; it < 2; ++it) {
    int idx = it * 512 + t, n = idx >> 4, j = idx & 15;
    *(bf16x8*)(theta_t + (((size_t)(b * Nc + n0 + n)) << 7) + j * 8) =
        *(const bf16x8*)(Yt + n * 136 + j * 8);
  }
  {
    int mloc = t >> 4, j = t & 15;
    const unsigned short* r0 = &PG[(2 * mloc) * 264 + j * 8];
    const unsigned short* r1 = &PG[(2 * mloc + 1) * 264 + j * 8];
    const unsigned short* r2 = &PG[(64 + 2 * mloc) * 264 + j * 8];
    const unsigned short* r3 = &PG[(65 + 2 * mloc) * 264 + j * 8];
    unsigned short o[8];
#pragma unroll
    for (int q = 0; q < 8; ++q)
      o[q] = f2bf(fmaxf(fmaxf(bf2f(r0[q]), bf2f(r1[q])),
                        fmaxf(bf2f(r2[q]), bf2f(r3[q]))));
    unsigned short* dp = phi_t + (((size_t)(b * Mc + h2 * 32 + mloc)) << 7) + j * 8;
    *(ushort4*)dp = *(ushort4*)o;
    *(ushort4*)(dp + 4) = *(ushort4*)(o + 4);
  }
  {
    int ci = t >> 2, mq = t & 3;
    unsigned short tmp[8];
#pragma unroll
    for (int q = 0; q < 8; ++q) {
      int w2 = mq * 8 + q;
      float m0 = fmaxf(
          fmaxf(bf2f(PG[(2 * w2) * 264 + 128 + ci]),
                bf2f(PG[(2 * w2 + 1) * 264 + 128 + ci])),
          fmaxf(bf2f(PG[(64 + 2 * w2) * 264 + 128 + ci]),
                bf2f(PG[(65 + 2 * w2) * 264 + 128 + ci])));
      tmp[q] = f2bf(m0);
    }
    unsigned short* dst = gbuf + ((size_t)(b * CIc + ci)) * Mc + h2 * 32 + mq * 8;
    *(ushort4*)(dst) = *(ushort4*)(tmp);
    *(ushort4*)(dst + 4) = *(ushort4*)(tmp + 4);
  }
  __syncthreads();
  if (w >= 4) {
#pragma unroll
    for (int tc = 0; tc < 8; ++tc) {
      float bv = bcat[tc * 16 + lr];
#pragma unroll
      for (int reg = 0; reg < 4; ++reg)
        Yt[((w - 4) * 16 + lg * 4 + reg) * 136 + tc * 16 + lr] =
            f2bf(acc[tc][reg] + bv);
    }
  }
  __syncthreads();
#pragma unroll
  for (int it = 0; it < 2; ++it) {
    int idx = it * 512 + t, n = idx >> 4, j = idx & 15;
    *(bf16x8*)(theta_t + (((size_t)(b * Nc + n0 + 64 + n)) << 7) + j * 8) =
        *(const bf16x8*)(Yt + n * 136 + j * 8);
  }
}

// ---------------------------------------------------------------------------
// Kernel 3: MFMA flash attention (round-10/11 structure: swapped QK^T +
// in-lane softmax, dbuf async staging). THIS ROUND: scores arrive in the
// log2 domain (theta pre-scaled by log2e), so exp() is a single raw
// v_exp_f32 (exp2) — no per-value multiply. Defer threshold 8 now bounds
// P by 2^8=256 (safer than before).
// ---------------------------------------------------------------------------
__global__ __launch_bounds__(256) void k_attn_mfma(
    const unsigned short* __restrict__ theta_t,
    const unsigned short* __restrict__ phi_t,
    const unsigned short* __restrict__ gv,
    unsigned short* __restrict__ y_t) {
  __shared__ __align__(16) char Kb[2][16384];   // [64 m][256B] swizzled
  __shared__ __align__(16) char Vb[2][16384];   // [128 ci][128B] swizzled
  __shared__ __align__(16) unsigned Psd[4][16][36];  // P dwords, 144B rows
  const int b = blockIdx.y, n0 = blockIdx.x * 64;
  const int tid = threadIdx.x;
  const int w = tid >> 6, l = tid & 63;
  const int lr = l & 15, lg = l >> 4;

  const int krow_l = l >> 4, kchunk = (l & 15) * 16;
  const int vrow_l = l >> 3, vchunk = (l & 7) * 16;
  int koff[4], voff[4];
#pragma unroll
  for (int i = 0; i < 4; ++i) {
    int kr = w * 16 + i * 4 + krow_l;
    koff[i] = kr * 256 + (kchunk ^ ((kr & 7) << 4));
    int vr = w * 32 + i * 8 + vrow_l;
    voff[i] = vr * 2048 + (vchunk ^ ((vr & 7) << 4));
  }
  const char* kbase = (const char*)(phi_t + (((size_t)(b * Mc)) << 7));
  const char* vbase = (const char*)(gv + (((size_t)b) << 17));

  auto stage = [&](int buf, int t) {
#pragma unroll
    for (int i = 0; i < 4; ++i)
      gload16(kbase + t * 16384 + koff[i], &Kb[buf][(w * 4 + i) * 1024]);
#pragma unroll
    for (int i = 0; i < 4; ++i)
      gload16(vbase + t * 128 + voff[i], &Vb[buf][(w * 4 + i) * 1024]);
  };

  bf16x8 qf[4];
  {
    const unsigned short* qp =
        theta_t + (((size_t)(b * Nc + n0 + w * 16 + lr)) << 7);
#pragma unroll
    for (int kk = 0; kk < 4; ++kk)
      qf[kk] = *(const bf16x8*)(qp + kk * 32 + lg * 8);
  }
  f32x4 of[8];
#pragma unroll
  for (int ct = 0; ct < 8; ++ct) of[ct] = (f32x4){0.f, 0.f, 0.f, 0.f};
  float run_m = -1e30f, run_l = 0.f;

  stage(0, 0);
  asm volatile("s_waitcnt vmcnt(0)" ::: "memory");
  __builtin_amdgcn_s_barrier();

  for (int t = 0; t < Mc / 64; ++t) {
    const int cur = t & 1;
    if (t + 1 < Mc / 64) stage(cur ^ 1, t + 1);
    const char* Ks = Kb[cur];
    const char* Vs = Vb[cur];
    f32x4 sm[4];
    __builtin_amdgcn_s_setprio(1);
#pragma unroll
    for (int mt = 0; mt < 4; ++mt) {
      f32x4 s = (f32x4){0.f, 0.f, 0.f, 0.f};
#pragma unroll
      for (int kk = 0; kk < 4; ++kk) {
        bf16x8 kf = *(const bf16x8*)(
            Ks + (mt * 16 + lr) * 256 + ((kk * 64 + lg * 16) ^ ((lr & 7) << 4)));
        s = __builtin_amdgcn_mfma_f32_16x16x32_bf16(kf, qf[kk], s, 0, 0, 0);
      }
      sm[mt] = s;
    }
    __builtin_amdgcn_s_setprio(0);
    float mx;
    {
      float m0 = fmaxf(fmaxf(sm[0][0], sm[0][1]), fmaxf(sm[0][2], sm[0][3]));
      float m1 = fmaxf(fmaxf(sm[1][0], sm[1][1]), fmaxf(sm[1][2], sm[1][3]));
      float m2 = fmaxf(fmaxf(sm[2][0], sm[2][1]), fmaxf(sm[2][2], sm[2][3]));
      float m3 = fmaxf(fmaxf(sm[3][0], sm[3][1]), fmaxf(sm[3][2], sm[3][3]));
      mx = fmaxf(fmaxf(m0, m1), fmaxf(m2, m3));
      mx = fmaxf(mx, __shfl_xor(mx, 16));
      mx = fmaxf(mx, __shfl_xor(mx, 32));
    }
    if (__any(mx > run_m + 8.f)) {
      float nm = fmaxf(run_m, mx);
      float sc = __builtin_amdgcn_exp2f(run_m - nm);
      run_m = nm;
      run_l *= sc;
#pragma unroll
      for (int reg = 0; reg < 4; ++reg) {
        float scr = __shfl(sc, lg * 20 + reg);
#pragma unroll
        for (int ct = 0; ct < 8; ++ct) of[ct][reg] *= scr;
      }
    }
    unsigned pk[4][2];
    float rowsum = 0.f;
#pragma unroll
    for (int mt = 0; mt < 4; ++mt) {
      float p0 = __builtin_amdgcn_exp2f(sm[mt][0] - run_m);
      float p1 = __builtin_amdgcn_exp2f(sm[mt][1] - run_m);
      float p2 = __builtin_amdgcn_exp2f(sm[mt][2] - run_m);
      float p3 = __builtin_amdgcn_exp2f(sm[mt][3] - run_m);
      rowsum += (p0 + p1) + (p2 + p3);
      asm("v_cvt_pk_bf16_f32 %0, %1, %2" : "=v"(pk[mt][0]) : "v"(p0), "v"(p1));
      asm("v_cvt_pk_bf16_f32 %0, %1, %2" : "=v"(pk[mt][1]) : "v"(p2), "v"(p3));
    }
    rowsum += __shfl_xor(rowsum, 16);
    rowsum += __shfl_xor(rowsum, 32);
    run_l += rowsum;
#pragma unroll
    for (int mt = 0; mt < 4; ++mt) {
      Psd[w][lr][8 * mt + 2 * lg + 0] = pk[mt][0];
      Psd[w][lr][8 * mt + 2 * lg + 1] = pk[mt][1];
    }
    bf16x8 pa0 = *(const bf16x8*)&Psd[w][lr][lg * 4];
    bf16x8 pa1 = *(const bf16x8*)&Psd[w][lr][16 + lg * 4];
    __builtin_amdgcn_s_setprio(1);
#pragma unroll
    for (int ct = 0; ct < 8; ++ct) {
      bf16x8 vf0 = *(const bf16x8*)(
          Vs + (ct * 16 + lr) * 128 + ((lg * 16) ^ ((lr & 7) << 4)));
      of[ct] = __builtin_amdgcn_mfma_f32_16x16x32_bf16(pa0, vf0, of[ct], 0, 0, 0);
      bf16x8 vf1 = *(const bf16x8*)(
          Vs + (ct * 16 + lr) * 128 + ((64 + lg * 16) ^ ((lr & 7) << 4)));
      of[ct] = __builtin_amdgcn_mfma_f32_16x16x32_bf16(pa1, vf1, of[ct], 0, 0, 0);
    }
    __builtin_amdgcn_s_setprio(0);
    asm volatile("s_waitcnt vmcnt(0)" ::: "memory");
    __builtin_amdgcn_s_barrier();
  }
  float invl = 1.f / run_l;
  float invr[4];
#pragma unroll
  for (int reg = 0; reg < 4; ++reg) invr[reg] = __shfl(invl, lg * 20 + reg);
  unsigned short* Ys = (unsigned short*)Kb;
#pragma unroll
  for (int ct = 0; ct < 8; ++ct)
#pragma unroll
    for (int reg = 0; reg < 4; ++reg)
      Ys[(w * 16 + lg * 4 + reg) * 128 + ct * 16 + lr] =
          f2bf(of[ct][reg] * invr[reg]);
  __syncthreads();
#pragma unroll
  for (int it = 0; it < 4; ++it) {
    int i = it * 256 + tid;
    int r = i >> 4, cl = i & 15;
    *(bf16x8*)(y_t + (((size_t)(b * Nc + n0 + r)) << 7) + cl * 8) =
        *(const bf16x8*)(Ys + r * 128 + cl * 8);
  }
}

// ---------------------------------------------------------------------------
// Kernel 4: MFMA W-conv + channels-first LayerNorm + residual.
// (unchanged from passing rounds 9-12: dbuf async W staging)
// ---------------------------------------------------------------------------
__global__ __launch_bounds__(256) void k_wconv_mfma(
    const unsigned short* __restrict__ y_t, const unsigned short* __restrict__ wwb,
    const float* __restrict__ wbias, const float* __restrict__ gamma,
    const float* __restrict__ beta, const float* __restrict__ x,
    float* __restrict__ out) {
  __shared__ __align__(16) char smem[65536];    // W dbuf [2][32768]; epilogue alias
  float* Ys = (float*)smem;                     // epilogue alias [128 c][72 n]
  const int b = blockIdx.y, n0 = blockIdx.x * 64;
  const int t = threadIdx.x;
  const int w = t >> 6, l = t & 63, lr = l & 15, lg = l >> 4;

  int woff[8];
#pragma unroll
  for (int i = 0; i < 8; ++i) {
    int r = (w * 8 + i) * 4 + (l >> 4);
    woff[i] = r * 256 + ((((l & 15) * 16)) ^ ((r & 7) << 4));
  }
  const char* wbase = (const char*)wwb;   // chunk cc at wbase + cc*32768

  auto stageW = [&](int buf, int cc) {
#pragma unroll
    for (int i = 0; i < 8; ++i)
      gload16(wbase + cc * 32768 + woff[i],
              smem + buf * 32768 + (w * 8 + i) * 1024);
  };

  bf16x8 qf[4];
  {
    const unsigned short* qp = y_t + (((size_t)(b * Nc + n0 + w * 16 + lr)) << 7);
#pragma unroll
    for (int kk = 0; kk < 4; ++kk)
      qf[kk] = *(const bf16x8*)(qp + kk * 32 + lg * 8);
  }
  f32x4 acc[32];
#pragma unroll
  for (int i = 0; i < 32; ++i) acc[i] = (f32x4){0.f, 0.f, 0.f, 0.f};

  stageW(0, 0);
  asm volatile("s_waitcnt vmcnt(0)" ::: "memory");
  __builtin_amdgcn_s_barrier();

#pragma unroll
  for (int cc = 0; cc < 4; ++cc) {
    const int cur = cc & 1;
    if (cc < 3) stageW(cur ^ 1, cc + 1);
    const char* WTs = smem + cur * 32768;
    __builtin_amdgcn_s_setprio(1);
#pragma unroll
    for (int tc = 0; tc < 8; ++tc) {
      f32x4 a = acc[cc * 8 + tc];
      int r = tc * 16 + lr;
#pragma unroll
      for (int kk = 0; kk < 4; ++kk) {
        bf16x8 kf = *(const bf16x8*)(
            WTs + r * 256 + ((kk * 64 + lg * 16) ^ ((lr & 7) << 4)));
        a = __builtin_amdgcn_mfma_f32_16x16x32_bf16(qf[kk], kf, a, 0, 0, 0);
      }
      acc[cc * 8 + tc] = a;
    }
    __builtin_amdgcn_s_setprio(0);
    asm volatile("s_waitcnt vmcnt(0)" ::: "memory");
    __builtin_amdgcn_s_barrier();
  }

  float s[4] = {0.f, 0.f, 0.f, 0.f}, q[4] = {0.f, 0.f, 0.f, 0.f};
#pragma unroll
  for (int cc = 0; cc < 4; ++cc)
#pragma unroll
    for (int tc = 0; tc < 8; ++tc) {
      float wb = wbias[cc * 128 + tc * 16 + lr];
      f32x4 a = acc[cc * 8 + tc];
#pragma unroll
      for (int reg = 0; reg < 4; ++reg) {
        a[reg] += wb;
        s[reg] += a[reg];
        q[reg] += a[reg] * a[reg];
      }
      acc[cc * 8 + tc] = a;
    }
  float mu[4], rs[4];
#pragma unroll
  for (int reg = 0; reg < 4; ++reg) {
    float sv = s[reg], qv = q[reg];
    sv += __shfl_xor(sv, 1); qv += __shfl_xor(qv, 1);
    sv += __shfl_xor(sv, 2); qv += __shfl_xor(qv, 2);
    sv += __shfl_xor(sv, 4); qv += __shfl_xor(qv, 4);
    sv += __shfl_xor(sv, 8); qv += __shfl_xor(qv, 8);
    mu[reg] = sv * (1.f / 512.f);
    float var = qv * (1.f / 512.f) - mu[reg] * mu[reg];
    rs[reg] = rsqrtf(var + 1e-5f);
  }
#pragma unroll
  for (int cc = 0; cc < 4; ++cc) {
    __syncthreads();
#pragma unroll
    for (int tc = 0; tc < 8; ++tc) {
      int c = cc * 128 + tc * 16 + lr;
      float ga = gamma[c], be = beta[c];
#pragma unroll
      for (int reg = 0; reg < 4; ++reg)
        Ys[(tc * 16 + lr) * 72 + w * 16 + lg * 4 + reg] =
            (acc[cc * 8 + tc][reg] - mu[reg]) * rs[reg] * ga + be;
    }
    __syncthreads();
#pragma unroll
    for (int it = 0; it < 8; ++it) {
      int idx = it * 256 + t;
      int r = idx >> 4, j = idx & 15;
      float4 v = *(const float4*)&Ys[r * 72 + j * 4];
      size_t gaddr = ((size_t)b * Cc + cc * 128 + r) * Nc + n0 + j * 4;
      float4 xv = *(const float4*)&x[gaddr];
      float4 o;
      o.x = v.x + xv.x; o.y = v.y + xv.y; o.z = v.z + xv.z; o.w = v.w + xv.w;
      *(float4*)&out[gaddr] = o;
    }
  }
}

// ---------------------------------------------------------------------------
extern "C" void kernel_launch(void* const* d_in, const int* in_sizes, int n_in,
                              void* d_out, int out_size, void* d_ws, size_t ws_size,
                              hipStream_t stream) {
  const float* x       = (const float*)d_in[0];
  const float* g_w     = (const float*)d_in[1];
  const float* g_b     = (const float*)d_in[2];
  const float* phi_w   = (const float*)d_in[3];
  const float* phi_b   = (const float*)d_in[4];
  const float* theta_w = (const float*)d_in[5];
  const float* theta_b = (const float*)d_in[6];
  const float* W_w     = (const float*)d_in[7];
  const float* W_b     = (const float*)d_in[8];
  const float* ln_g    = (const float*)d_in[9];
  const float* ln_b    = (const float*)d_in[10];
  float* out = (float*)d_out;

  unsigned short* theta_t = (unsigned short*)d_ws;
  unsigned short* y_t     = theta_t + (size_t)Bc * Nc * CIc;
  unsigned short* phi_t   = y_t + (size_t)Bc * Nc * CIc;
  unsigned short* gbuf    = phi_t + (size_t)Bc * Mc * CIc;
  unsigned short* wcat    = gbuf + (size_t)Bc * Mc * CIc;
  unsigned short* wwb     = wcat + (size_t)384 * 512;
  float*          bcat    = (float*)(wwb + (size_t)512 * 128);

  k_prep<<<dim3(258), dim3(256), 0, stream>>>(
      g_w, phi_w, theta_w, W_w, g_b, phi_b, theta_b, wcat, wwb, bcat);
  k_conv_all<<<dim3(Nc / 128, Bc), dim3(512), 0, stream>>>(
      x, wcat, bcat, theta_t, phi_t, gbuf);
  k_attn_mfma<<<dim3(Nc / 64, Bc), dim3(256), 0, stream>>>(
      theta_t, phi_t, gbuf, y_t);
  k_wconv_mfma<<<dim3(Nc / 64, Bc), dim3(256), 0, stream>>>(
      y_t, wwb, W_b, ln_g, ln_b, x, out);
}